// Round 6
// baseline (569.395 us; speedup 1.0000x reference)
//
#include <hip/hip_runtime.h>

#define ND 100000
#define DD 128
#define HH 256
#define EE 640000
#define LL 5

typedef __attribute__((ext_vector_type(8))) short short8;
typedef __attribute__((ext_vector_type(4))) short short4v;
typedef __attribute__((ext_vector_type(4))) float f32x4;

static __device__ __forceinline__ short f2bf(float f) {
    unsigned u = __builtin_bit_cast(unsigned, f);
    unsigned r = (u + 0x7fffu + ((u >> 16) & 1u)) >> 16;
    return (short)r;
}
static __device__ __forceinline__ float bf2f(short s) {
    unsigned u = ((unsigned)(unsigned short)s) << 16;
    return __builtin_bit_cast(float, u);
}

// ---------------------------------------------------------------------------
// setup: blocks [0,640) fold BN into weights (bf16 [n][k] pack);
//        blocks [640,13140) convert x fp32 -> bf16 into hbufA;
//        blocks [13140,15640) histogram dst degrees (cnt pre-zeroed).
// ---------------------------------------------------------------------------
__global__ __launch_bounds__(256) void setup(
    const float* __restrict__ W1, const float* __restrict__ b1,
    const float* __restrict__ g1, const float* __restrict__ bb1,
    const float* __restrict__ m1, const float* __restrict__ v1,
    const float* __restrict__ W2, const float* __restrict__ b2,
    const float* __restrict__ g2, const float* __restrict__ bb2,
    const float* __restrict__ m2, const float* __restrict__ v2,
    const float* __restrict__ x, const int* __restrict__ dst,
    short* __restrict__ W1p, float* __restrict__ b1e,
    short* __restrict__ W2p, float* __restrict__ b2e,
    short* __restrict__ hb, int* __restrict__ cnt)
{
    int bx = blockIdx.x;
    int tid = threadIdx.x;
    if (bx < 640) {
        int id = bx * 256 + tid;
        if (id < LL * HH * DD) {
            int l = id >> 15;
            int rem = id & 32767;
            {
                int n = rem >> 7, k = rem & 127;
                float s = g1[l * HH + n] * rsqrtf(v1[l * HH + n] + 1e-5f);
                W1p[id] = f2bf(W1[l * 32768 + k * HH + n] * s);
            }
            {
                int n2 = rem >> 8, k2 = rem & 255;
                float s = g2[l * DD + n2] * rsqrtf(v2[l * DD + n2] + 1e-5f);
                W2p[id] = f2bf(W2[l * 32768 + k2 * DD + n2] * s);
            }
        }
        if (id < LL * HH) {
            float s = g1[id] * rsqrtf(v1[id] + 1e-5f);
            b1e[id] = (b1[id] - m1[id]) * s + bb1[id];
        }
        if (id < LL * DD) {
            float s = g2[id] * rsqrtf(v2[id] + 1e-5f);
            b2e[id] = (b2[id] - m2[id]) * s + bb2[id];
        }
    } else if (bx < 13140) {
        int i = (bx - 640) * 256 + tid;          // ND*DD/4 = 3,200,000 float4s
        float4 v = reinterpret_cast<const float4*>(x)[i];
        short4v s;
        s.x = f2bf(v.x); s.y = f2bf(v.y); s.z = f2bf(v.z); s.w = f2bf(v.w);
        reinterpret_cast<short4v*>(hb)[i] = s;
    } else {
        int e = (bx - 13140) * 256 + tid;
        if (e < EE) atomicAdd(&cnt[dst[e]], 1);
    }
}

// per-block inclusive scan of cnt (in place) + block totals
__global__ __launch_bounds__(256) void scan_block(int* __restrict__ cnt, int* __restrict__ bsum)
{
    __shared__ int buf[256];
    int tid = threadIdx.x;
    int idx = blockIdx.x * 256 + tid;
    int v = (idx < ND) ? cnt[idx] : 0;
    buf[tid] = v;
    __syncthreads();
    int sum = v;
    for (int off = 1; off < 256; off <<= 1) {
        int t = (tid >= off) ? buf[tid - off] : 0;
        __syncthreads();
        sum += t;
        buf[tid] = sum;
        __syncthreads();
    }
    if (idx < ND) cnt[idx] = sum;
    if (tid == 255) bsum[blockIdx.x] = sum;
}

__global__ __launch_bounds__(512) void scan_bsum(const int* __restrict__ bsum,
                                                 int* __restrict__ boffs)
{
    __shared__ int buf[512];
    int tid = threadIdx.x;
    int v = (tid < 391) ? bsum[tid] : 0;
    buf[tid] = v;
    __syncthreads();
    int sum = v;
    for (int off = 1; off < 512; off <<= 1) {
        int t = (tid >= off) ? buf[tid - off] : 0;
        __syncthreads();
        sum += t;
        buf[tid] = sum;
        __syncthreads();
    }
    if (tid < 391) boffs[tid] = sum - v;   // exclusive block offset
}

__global__ __launch_bounds__(256) void apply_offs(const int* __restrict__ cnt,
                                                  const int* __restrict__ boffs,
                                                  int* __restrict__ rowst)
{
    int idx = blockIdx.x * 256 + threadIdx.x;
    if (idx < ND) rowst[idx + 1] = cnt[idx] + boffs[blockIdx.x];
    if (idx == 0) rowst[0] = 0;
}

__global__ __launch_bounds__(256) void fill_csr(const int* __restrict__ src,
                                                const int* __restrict__ dst,
                                                const int* __restrict__ rowstart,
                                                int* __restrict__ cursor,
                                                int* __restrict__ csr)
{
    int e = blockIdx.x * 256 + threadIdx.x;
    if (e < EE) {
        int d = dst[e];
        int p = atomicAdd(&cursor[d], 1);
        csr[rowstart[d] + p] = src[e];
    }
}

// ---------------------------------------------------------------------------
// Fused GIN layer, 1024 threads (16 waves) per 64-row block:
//   gather (1 chunk/thread, no serial loop) -> LDS ->
//   zT = W1(A) x agg(B) (wave: 16 zcols x 64 nodes) -> LDS ->
//   hT = W2(A) x z(B)   (wave: 16 outcols x 32 nodes) -> stores.
// hb_in != hb_out (cross-block WAR hazard — R3 failure).
// LDS union: gather view stride 136 (17.4 KB), z view stride 264 (33.8 KB).
// 2 blocks/CU = 32 waves/CU (launch_bounds caps VGPR at 64).
// ---------------------------------------------------------------------------
__global__ __launch_bounds__(1024, 8) void layer_fused(
    const short* __restrict__ hb_in,
    const int* __restrict__ rowst,
    const int* __restrict__ csr,
    const short* __restrict__ W1l,    // [256][128] bf16
    const float* __restrict__ b1l,    // [256]
    const short* __restrict__ W2l,    // [128][256] bf16
    const float* __restrict__ b2l,    // [128]
    short* __restrict__ hb_out, float* __restrict__ f_out, int last)
{
    __shared__ __attribute__((aligned(16))) short sU[64 * 264];

    const int tid = threadIdx.x;
    const int r0 = blockIdx.x * 64;
    const int wave = tid >> 6;
    const int lane = tid & 63;
    const int quad = lane >> 4;
    const int l16 = lane & 15;

    // ---- Stage A: neighbor gather, exactly one row-chunk per thread ----
    {
        int row = tid >> 4;           // 0..63
        int ch = (tid & 15) * 8;      // 0,8,...,120
        int grow = r0 + row;
        float acc[8];
        if (grow < ND) {
            short8 h0 = *reinterpret_cast<const short8*>(&hb_in[(size_t)grow * DD + ch]);
            for (int j = 0; j < 8; ++j) acc[j] = bf2f(h0[j]);
            int s = rowst[grow], e = rowst[grow + 1];
            int i = s;
            for (; i + 1 < e; i += 2) {
                int s0 = csr[i], s1 = csr[i + 1];
                short8 a = *reinterpret_cast<const short8*>(&hb_in[(size_t)s0 * DD + ch]);
                short8 b = *reinterpret_cast<const short8*>(&hb_in[(size_t)s1 * DD + ch]);
                for (int j = 0; j < 8; ++j) acc[j] += bf2f(a[j]) + bf2f(b[j]);
            }
            if (i < e) {
                short8 a = *reinterpret_cast<const short8*>(&hb_in[(size_t)csr[i] * DD + ch]);
                for (int j = 0; j < 8; ++j) acc[j] += bf2f(a[j]);
            }
        } else {
            for (int j = 0; j < 8; ++j) acc[j] = 0.f;
        }
        short8 o;
        for (int j = 0; j < 8; ++j) o[j] = f2bf(acc[j]);
        *reinterpret_cast<short8*>(&sU[row * 136 + ch]) = o;
    }
    __syncthreads();

    // ---- Stage B: GEMM1' — wave owns zcols [wave*16, wave*16+16) x 64 nodes ----
    const f32x4 zero4 = {0.f, 0.f, 0.f, 0.f};
    f32x4 acc1[4];    // node tiles nt=0..3
    for (int nt = 0; nt < 4; ++nt) acc1[nt] = zero4;

    const int zrow = wave * 16 + l16;   // W1 row (zcol) this lane loads
    for (int ks = 0; ks < 4; ++ks) {
        int kofs = ks * 32 + quad * 8;
        short8 aw = *reinterpret_cast<const short8*>(&W1l[zrow * DD + kofs]);
        for (int nt = 0; nt < 4; ++nt) {
            short8 bn = *reinterpret_cast<const short8*>(&sU[(nt * 16 + l16) * 136 + kofs]);
            acc1[nt] = __builtin_amdgcn_mfma_f32_16x16x32_bf16(aw, bn, acc1[nt], 0, 0, 0);
        }
    }
    __syncthreads();   // gather view dead; z view reuses LDS

    // ---- Stage C: bias + ReLU -> sU[node][zcol] (stride 264), b64 writes ----
    {
        int zc = wave * 16 + quad * 4;
        float4 bias = *reinterpret_cast<const float4*>(&b1l[zc]);
        for (int nt = 0; nt < 4; ++nt) {
            int node = nt * 16 + l16;
            short4v o;
            o.x = f2bf(fmaxf(acc1[nt][0] + bias.x, 0.f));
            o.y = f2bf(fmaxf(acc1[nt][1] + bias.y, 0.f));
            o.z = f2bf(fmaxf(acc1[nt][2] + bias.z, 0.f));
            o.w = f2bf(fmaxf(acc1[nt][3] + bias.w, 0.f));
            *reinterpret_cast<short4v*>(&sU[node * 264 + zc]) = o;
        }
    }
    __syncthreads();

    // ---- Stage D: GEMM2' — wave (ct16 = wave>>1, nh = wave&1) owns
    //      outcols [ct16*16, +16) x nodes [nh*32, +32) ----
    f32x4 acc2[2];
    for (int nt = 0; nt < 2; ++nt) acc2[nt] = zero4;

    const int ct16 = wave >> 1;
    const int nh = wave & 1;
    const int orow = ct16 * 16 + l16;   // W2 row (outcol) this lane loads
    for (int ks = 0; ks < 8; ++ks) {
        int kofs = ks * 32 + quad * 8;
        short8 aw = *reinterpret_cast<const short8*>(&W2l[orow * HH + kofs]);
        for (int nt = 0; nt < 2; ++nt) {
            int node = nh * 32 + nt * 16 + l16;
            short8 bn = *reinterpret_cast<const short8*>(&sU[node * 264 + kofs]);
            acc2[nt] = __builtin_amdgcn_mfma_f32_16x16x32_bf16(aw, bn, acc2[nt], 0, 0, 0);
        }
    }

    // ---- Stage E: bias (+ReLU) -> vectorized global stores ----
    {
        int oc = ct16 * 16 + quad * 4;
        float4 bias = *reinterpret_cast<const float4*>(&b2l[oc]);
        for (int nt = 0; nt < 2; ++nt) {
            int node = r0 + nh * 32 + nt * 16 + l16;
            if (node < ND) {
                float v0 = acc2[nt][0] + bias.x;
                float v1 = acc2[nt][1] + bias.y;
                float v2 = acc2[nt][2] + bias.z;
                float v3 = acc2[nt][3] + bias.w;
                if (!last) {
                    short4v o;
                    o.x = f2bf(fmaxf(v0, 0.f));
                    o.y = f2bf(fmaxf(v1, 0.f));
                    o.z = f2bf(fmaxf(v2, 0.f));
                    o.w = f2bf(fmaxf(v3, 0.f));
                    *reinterpret_cast<short4v*>(&hb_out[(size_t)node * DD + oc]) = o;
                } else {
                    float4 st; st.x = v0; st.y = v1; st.z = v2; st.w = v3;
                    *reinterpret_cast<float4*>(&f_out[(size_t)node * DD + oc]) = st;
                }
            }
        }
    }
}

extern "C" void kernel_launch(void* const* d_in, const int* in_sizes, int n_in,
                              void* d_out, int out_size, void* d_ws, size_t ws_size,
                              hipStream_t stream)
{
    const float* x  = (const float*)d_in[0];
    const int* ei   = (const int*)d_in[1];
    const int* src  = ei;
    const int* dst  = ei + EE;
    const float* W1 = (const float*)d_in[2];
    const float* b1 = (const float*)d_in[3];
    const float* g1 = (const float*)d_in[4];
    const float* bb1= (const float*)d_in[5];
    const float* m1 = (const float*)d_in[6];
    const float* v1 = (const float*)d_in[7];
    const float* W2 = (const float*)d_in[8];
    const float* b2 = (const float*)d_in[9];
    const float* g2 = (const float*)d_in[10];
    const float* bb2= (const float*)d_in[11];
    const float* m2 = (const float*)d_in[12];
    const float* v2 = (const float*)d_in[13];

    char* w = (char*)d_ws;
    short* hbufA = (short*)w;                                 // 25,600,000
    short* hbufB = (short*)(w + 25600000);                    // 25,600,000
    short* W1p   = (short*)(w + 51200000);                    //    327,680
    short* W2p   = (short*)(w + 51527680);                    //    327,680
    float* b1e   = (float*)(w + 51855360);                    //      5,120
    float* b2e   = (float*)(w + 51860480);                    //      2,560
    int*   cnt   = (int*)  (w + 51863040);                    //    400,000
    int*   cursor= (int*)  (w + 52263040);                    //    400,000 (contiguous after cnt)
    int*   rowst = (int*)  (w + 52663040);                    //    400,032
    int*   csr   = (int*)  (w + 53063072);                    //  2,560,000
    int*   bsum  = (int*)  (w + 55623072);                    //      1,664
    int*   boffs = (int*)  (w + 55624736);                    //      1,600
    float* out   = (float*)d_out;

    // zero cnt + cursor (contiguous 800,000 B) — capture-safe async memset
    hipMemsetAsync(cnt, 0, 800000, stream);
    setup<<<15640, 256, 0, stream>>>(W1, b1, g1, bb1, m1, v1,
                                     W2, b2, g2, bb2, m2, v2,
                                     x, dst, W1p, b1e, W2p, b2e, hbufA, cnt);
    scan_block<<<391, 256, 0, stream>>>(cnt, bsum);
    scan_bsum<<<1, 512, 0, stream>>>(bsum, boffs);
    apply_offs<<<391, 256, 0, stream>>>(cnt, boffs, rowst);
    fill_csr<<<2500, 256, 0, stream>>>(src, dst, rowst, cursor, csr);

    short* hin = hbufA;
    short* hout = hbufB;
    for (int l = 0; l < LL; ++l) {
        layer_fused<<<1563, 1024, 0, stream>>>(hin, rowst, csr,
                                               W1p + l * 32768, b1e + l * HH,
                                               W2p + l * 32768, b2e + l * DD,
                                               hout, out, (l == LL - 1) ? 1 : 0);
        short* t = hin; hin = hout; hout = t;
    }
}

// Round 7
// 551.552 us; speedup vs baseline: 1.0324x; 1.0324x over previous
//
#include <hip/hip_runtime.h>

#define ND 100000
#define DD 128
#define HH 256
#define EE 640000
#define LL 5

typedef __attribute__((ext_vector_type(8))) short short8;
typedef __attribute__((ext_vector_type(4))) short short4v;
typedef __attribute__((ext_vector_type(4))) float f32x4;

static __device__ __forceinline__ short f2bf(float f) {
    unsigned u = __builtin_bit_cast(unsigned, f);
    unsigned r = (u + 0x7fffu + ((u >> 16) & 1u)) >> 16;
    return (short)r;
}
static __device__ __forceinline__ float bf2f(short s) {
    unsigned u = ((unsigned)(unsigned short)s) << 16;
    return __builtin_bit_cast(float, u);
}

// ---------------------------------------------------------------------------
// setup: blocks [0,640) fold BN into weights (bf16 [n][k] pack);
//        blocks [640,13140) convert x fp32 -> bf16 into hbufA;
//        blocks [13140,15640) histogram dst degrees (cnt pre-zeroed).
// ---------------------------------------------------------------------------
__global__ __launch_bounds__(256) void setup(
    const float* __restrict__ W1, const float* __restrict__ b1,
    const float* __restrict__ g1, const float* __restrict__ bb1,
    const float* __restrict__ m1, const float* __restrict__ v1,
    const float* __restrict__ W2, const float* __restrict__ b2,
    const float* __restrict__ g2, const float* __restrict__ bb2,
    const float* __restrict__ m2, const float* __restrict__ v2,
    const float* __restrict__ x, const int* __restrict__ dst,
    short* __restrict__ W1p, float* __restrict__ b1e,
    short* __restrict__ W2p, float* __restrict__ b2e,
    short* __restrict__ hb, int* __restrict__ cnt)
{
    int bx = blockIdx.x;
    int tid = threadIdx.x;
    if (bx < 640) {
        int id = bx * 256 + tid;
        if (id < LL * HH * DD) {
            int l = id >> 15;
            int rem = id & 32767;
            {
                int n = rem >> 7, k = rem & 127;
                float s = g1[l * HH + n] * rsqrtf(v1[l * HH + n] + 1e-5f);
                W1p[id] = f2bf(W1[l * 32768 + k * HH + n] * s);
            }
            {
                int n2 = rem >> 8, k2 = rem & 255;
                float s = g2[l * DD + n2] * rsqrtf(v2[l * DD + n2] + 1e-5f);
                W2p[id] = f2bf(W2[l * 32768 + k2 * DD + n2] * s);
            }
        }
        if (id < LL * HH) {
            float s = g1[id] * rsqrtf(v1[id] + 1e-5f);
            b1e[id] = (b1[id] - m1[id]) * s + bb1[id];
        }
        if (id < LL * DD) {
            float s = g2[id] * rsqrtf(v2[id] + 1e-5f);
            b2e[id] = (b2[id] - m2[id]) * s + bb2[id];
        }
    } else if (bx < 13140) {
        int i = (bx - 640) * 256 + tid;          // ND*DD/4 = 3,200,000 float4s
        float4 v = reinterpret_cast<const float4*>(x)[i];
        short4v s;
        s.x = f2bf(v.x); s.y = f2bf(v.y); s.z = f2bf(v.z); s.w = f2bf(v.w);
        reinterpret_cast<short4v*>(hb)[i] = s;
    } else {
        int e = (bx - 13140) * 256 + tid;
        if (e < EE) atomicAdd(&cnt[dst[e]], 1);
    }
}

// per-block inclusive scan of cnt (in place) + block totals
__global__ __launch_bounds__(256) void scan_block(int* __restrict__ cnt, int* __restrict__ bsum)
{
    __shared__ int buf[256];
    int tid = threadIdx.x;
    int idx = blockIdx.x * 256 + tid;
    int v = (idx < ND) ? cnt[idx] : 0;
    buf[tid] = v;
    __syncthreads();
    int sum = v;
    for (int off = 1; off < 256; off <<= 1) {
        int t = (tid >= off) ? buf[tid - off] : 0;
        __syncthreads();
        sum += t;
        buf[tid] = sum;
        __syncthreads();
    }
    if (idx < ND) cnt[idx] = sum;
    if (tid == 255) bsum[blockIdx.x] = sum;
}

// merged: each block computes its exclusive prefix over bsum, then rowst
__global__ __launch_bounds__(256) void apply_offs2(const int* __restrict__ cnt,
                                                   const int* __restrict__ bsum,
                                                   int* __restrict__ rowst)
{
    __shared__ int sred[256];
    int tid = threadIdx.x;
    int partial = 0;
    for (int i = tid; i < blockIdx.x; i += 256) partial += bsum[i];
    sred[tid] = partial;
    __syncthreads();
    for (int off = 128; off > 0; off >>= 1) {
        if (tid < off) sred[tid] += sred[tid + off];
        __syncthreads();
    }
    int boff = sred[0];
    int idx = blockIdx.x * 256 + tid;
    if (idx < ND) rowst[idx + 1] = cnt[idx] + boff;
    if (idx == 0) rowst[0] = 0;
}

__global__ __launch_bounds__(256) void fill_csr(const int* __restrict__ src,
                                                const int* __restrict__ dst,
                                                const int* __restrict__ rowstart,
                                                int* __restrict__ cursor,
                                                int* __restrict__ csr)
{
    int e = blockIdx.x * 256 + threadIdx.x;
    if (e < EE) {
        int d = dst[e];
        int p = atomicAdd(&cursor[d], 1);
        csr[rowstart[d] + p] = src[e];
    }
}

// ---------------------------------------------------------------------------
// Fused GIN layer, 1024 threads (16 waves) per 64-row block.
//   Stage A: gather, ONE chunk/thread, neighbor loop unrolled x4 with
//            batched independent loads (4 rows in flight per waitcnt).
//   GEMM1: wave owns 16 zcols x 64 nodes; all 4 W1 fragments preloaded
//          BEFORE the gather barrier (independent, L2-hot).
//   GEMM2: wave owns 16 outcols x 32 nodes; W2 fragments software-pipelined.
// hb_in != hb_out (cross-block WAR hazard — R3 failure).
// LDS union: gather view stride 136, z view stride 264 (33,792 B).
// ---------------------------------------------------------------------------
__global__ __launch_bounds__(1024, 8) void layer_fused(
    const short* __restrict__ hb_in,
    const int* __restrict__ rowst,
    const int* __restrict__ csr,
    const short* __restrict__ W1l,    // [256][128] bf16
    const float* __restrict__ b1l,    // [256]
    const short* __restrict__ W2l,    // [128][256] bf16
    const float* __restrict__ b2l,    // [128]
    short* __restrict__ hb_out, float* __restrict__ f_out, int last)
{
    __shared__ __attribute__((aligned(16))) short sU[64 * 264];

    const int tid = threadIdx.x;
    const int r0 = blockIdx.x * 64;
    const int wave = tid >> 6;
    const int lane = tid & 63;
    const int quad = lane >> 4;
    const int l16 = lane & 15;

    // Preload GEMM1 weight fragments + bias (independent of gather)
    const int zrow = wave * 16 + l16;
    short8 aw1[4];
    for (int ks = 0; ks < 4; ++ks)
        aw1[ks] = *reinterpret_cast<const short8*>(&W1l[zrow * DD + ks * 32 + quad * 8]);
    float4 bias1 = *reinterpret_cast<const float4*>(&b1l[wave * 16 + quad * 4]);

    // ---- Stage A: neighbor gather, unroll-4 batched loads ----
    {
        int row = tid >> 4;           // 0..63
        int ch = (tid & 15) * 8;      // 0,8,...,120
        int grow = r0 + row;
        float acc[8];
        if (grow < ND) {
            short8 h0 = *reinterpret_cast<const short8*>(&hb_in[(size_t)grow * DD + ch]);
            for (int j = 0; j < 8; ++j) acc[j] = bf2f(h0[j]);
            int s = rowst[grow], e = rowst[grow + 1];
            int i = s;
            for (; i + 3 < e; i += 4) {
                int s0 = csr[i], s1 = csr[i + 1], s2 = csr[i + 2], s3 = csr[i + 3];
                short8 a0 = *reinterpret_cast<const short8*>(&hb_in[(size_t)s0 * DD + ch]);
                short8 a1 = *reinterpret_cast<const short8*>(&hb_in[(size_t)s1 * DD + ch]);
                short8 a2 = *reinterpret_cast<const short8*>(&hb_in[(size_t)s2 * DD + ch]);
                short8 a3 = *reinterpret_cast<const short8*>(&hb_in[(size_t)s3 * DD + ch]);
                for (int j = 0; j < 8; ++j)
                    acc[j] += (bf2f(a0[j]) + bf2f(a1[j])) + (bf2f(a2[j]) + bf2f(a3[j]));
            }
            for (; i < e; ++i) {
                short8 a = *reinterpret_cast<const short8*>(&hb_in[(size_t)csr[i] * DD + ch]);
                for (int j = 0; j < 8; ++j) acc[j] += bf2f(a[j]);
            }
        } else {
            for (int j = 0; j < 8; ++j) acc[j] = 0.f;
        }
        short8 o;
        for (int j = 0; j < 8; ++j) o[j] = f2bf(acc[j]);
        *reinterpret_cast<short8*>(&sU[row * 136 + ch]) = o;
    }
    __syncthreads();

    // ---- GEMM1' zT = W1(A) x agg(B): wave owns zcols [wave*16,+16) x 64 nodes ----
    const f32x4 zero4 = {0.f, 0.f, 0.f, 0.f};
    f32x4 acc1[4];
    for (int nt = 0; nt < 4; ++nt) acc1[nt] = zero4;

    for (int ks = 0; ks < 4; ++ks) {
        int kofs = ks * 32 + quad * 8;
        for (int nt = 0; nt < 4; ++nt) {
            short8 bn = *reinterpret_cast<const short8*>(&sU[(nt * 16 + l16) * 136 + kofs]);
            acc1[nt] = __builtin_amdgcn_mfma_f32_16x16x32_bf16(aw1[ks], bn, acc1[nt], 0, 0, 0);
        }
    }
    __syncthreads();   // gather view dead; z view reuses LDS

    // ---- Stage C: bias + ReLU -> sU[node][zcol] (stride 264), b64 writes ----
    {
        int zc = wave * 16 + quad * 4;
        for (int nt = 0; nt < 4; ++nt) {
            int node = nt * 16 + l16;
            short4v o;
            o.x = f2bf(fmaxf(acc1[nt][0] + bias1.x, 0.f));
            o.y = f2bf(fmaxf(acc1[nt][1] + bias1.y, 0.f));
            o.z = f2bf(fmaxf(acc1[nt][2] + bias1.z, 0.f));
            o.w = f2bf(fmaxf(acc1[nt][3] + bias1.w, 0.f));
            *reinterpret_cast<short4v*>(&sU[node * 264 + zc]) = o;
        }
    }

    // Preload GEMM2 first weight fragment + bias while barrier settles
    const int ct16 = wave >> 1;
    const int nh = wave & 1;
    const int orow = ct16 * 16 + l16;
    short8 w_cur = *reinterpret_cast<const short8*>(&W2l[orow * HH + quad * 8]);
    float4 bias2 = *reinterpret_cast<const float4*>(&b2l[ct16 * 16 + quad * 4]);
    __syncthreads();

    // ---- GEMM2' hT = W2(A) x z(B): wave owns outcols [ct16*16,+16) x 32 nodes,
    //      W2 fragments software-pipelined ----
    f32x4 acc2[2];
    for (int nt = 0; nt < 2; ++nt) acc2[nt] = zero4;

    for (int ks = 0; ks < 8; ++ks) {
        short8 w_next;
        if (ks < 7)
            w_next = *reinterpret_cast<const short8*>(&W2l[orow * HH + (ks + 1) * 32 + quad * 8]);
        int kofs = ks * 32 + quad * 8;
        for (int nt = 0; nt < 2; ++nt) {
            int node = nh * 32 + nt * 16 + l16;
            short8 bn = *reinterpret_cast<const short8*>(&sU[node * 264 + kofs]);
            acc2[nt] = __builtin_amdgcn_mfma_f32_16x16x32_bf16(w_cur, bn, acc2[nt], 0, 0, 0);
        }
        w_cur = w_next;
    }

    // ---- Stage E: bias (+ReLU) -> vectorized global stores ----
    {
        int oc = ct16 * 16 + quad * 4;
        for (int nt = 0; nt < 2; ++nt) {
            int node = r0 + nh * 32 + nt * 16 + l16;
            if (node < ND) {
                float v0 = acc2[nt][0] + bias2.x;
                float v1 = acc2[nt][1] + bias2.y;
                float v2 = acc2[nt][2] + bias2.z;
                float v3 = acc2[nt][3] + bias2.w;
                if (!last) {
                    short4v o;
                    o.x = f2bf(fmaxf(v0, 0.f));
                    o.y = f2bf(fmaxf(v1, 0.f));
                    o.z = f2bf(fmaxf(v2, 0.f));
                    o.w = f2bf(fmaxf(v3, 0.f));
                    *reinterpret_cast<short4v*>(&hb_out[(size_t)node * DD + oc]) = o;
                } else {
                    float4 st; st.x = v0; st.y = v1; st.z = v2; st.w = v3;
                    *reinterpret_cast<float4*>(&f_out[(size_t)node * DD + oc]) = st;
                }
            }
        }
    }
}

extern "C" void kernel_launch(void* const* d_in, const int* in_sizes, int n_in,
                              void* d_out, int out_size, void* d_ws, size_t ws_size,
                              hipStream_t stream)
{
    const float* x  = (const float*)d_in[0];
    const int* ei   = (const int*)d_in[1];
    const int* src  = ei;
    const int* dst  = ei + EE;
    const float* W1 = (const float*)d_in[2];
    const float* b1 = (const float*)d_in[3];
    const float* g1 = (const float*)d_in[4];
    const float* bb1= (const float*)d_in[5];
    const float* m1 = (const float*)d_in[6];
    const float* v1 = (const float*)d_in[7];
    const float* W2 = (const float*)d_in[8];
    const float* b2 = (const float*)d_in[9];
    const float* g2 = (const float*)d_in[10];
    const float* bb2= (const float*)d_in[11];
    const float* m2 = (const float*)d_in[12];
    const float* v2 = (const float*)d_in[13];

    char* w = (char*)d_ws;
    short* hbufA = (short*)w;                                 // 25,600,000
    short* hbufB = (short*)(w + 25600000);                    // 25,600,000
    short* W1p   = (short*)(w + 51200000);                    //    327,680
    short* W2p   = (short*)(w + 51527680);                    //    327,680
    float* b1e   = (float*)(w + 51855360);                    //      5,120
    float* b2e   = (float*)(w + 51860480);                    //      2,560
    int*   cnt   = (int*)  (w + 51863040);                    //    400,000
    int*   cursor= (int*)  (w + 52263040);                    //    400,000 (contiguous after cnt)
    int*   rowst = (int*)  (w + 52663040);                    //    400,032
    int*   csr   = (int*)  (w + 53063072);                    //  2,560,000
    int*   bsum  = (int*)  (w + 55623072);                    //      1,664
    float* out   = (float*)d_out;

    // zero cnt + cursor (contiguous 800,000 B) — capture-safe async memset
    hipMemsetAsync(cnt, 0, 800000, stream);
    setup<<<15640, 256, 0, stream>>>(W1, b1, g1, bb1, m1, v1,
                                     W2, b2, g2, bb2, m2, v2,
                                     x, dst, W1p, b1e, W2p, b2e, hbufA, cnt);
    scan_block<<<391, 256, 0, stream>>>(cnt, bsum);
    apply_offs2<<<391, 256, 0, stream>>>(cnt, bsum, rowst);
    fill_csr<<<2500, 256, 0, stream>>>(src, dst, rowst, cursor, csr);

    short* hin = hbufA;
    short* hout = hbufB;
    for (int l = 0; l < LL; ++l) {
        layer_fused<<<1563, 1024, 0, stream>>>(hin, rowst, csr,
                                               W1p + l * 32768, b1e + l * HH,
                                               W2p + l * 32768, b2e + l * DD,
                                               hout, out, (l == LL - 1) ? 1 : 0);
        short* t = hin; hin = hout; hout = t;
    }
}